// Round 3
// baseline (302.808 us; speedup 1.0000x reference)
//
#include <hip/hip_runtime.h>
#include <hip/hip_bf16.h>
#include <stdint.h>

#define B_ROWS 4096
#define L_FEAT 256
#define VOCAB  8192

#define BM 128
#define BN 128
#define BK 64        // int8 MFMA K per iteration
#define NTILE 32     // 4096/128
#define NTRI  528    // NTILE*(NTILE+1)/2
#define KSPLIT 4096  // K per slab

typedef __attribute__((ext_vector_type(4))) int intx4;

__device__ __forceinline__ void async_copy16(const void* gsrc, void* ldst) {
  __builtin_amdgcn_global_load_lds(
      (const __attribute__((address_space(1))) void*)gsrc,
      (__attribute__((address_space(3))) void*)ldst, 16, 0, 0);
}

__device__ __forceinline__ int tri_index(int a, int b) {  // a<=b
  return a * NTILE - (a * (a - 1)) / 2 + (b - a);
}

// ---------------- kernel 1: zero the presence matrix (32 MB int8) ------------
__global__ void zero_kernel(uint4* __restrict__ p, int n16) {
  int i = blockIdx.x * blockDim.x + threadIdx.x;
  const int stride = gridDim.x * blockDim.x;
  const uint4 z = make_uint4(0u, 0u, 0u, 0u);
  for (; i < n16; i += stride) p[i] = z;
}

// ---------------- kernel 2: scatter ones (int8) ------------------------------
__global__ void scatter_kernel(const int* __restrict__ f,
                               unsigned char* __restrict__ P) {
  const int id  = blockIdx.x * 256 + threadIdx.x;
  const int row = id >> 8;
  const int v   = f[id];
  P[(size_t)row * VOCAB + v] = 1;
}

// ---------------- kernel 3: per-row set sizes --------------------------------
__global__ void sizes_kernel(const uint4* __restrict__ P4,
                             float* __restrict__ sizes) {
  const int row = blockIdx.x;
  const uint4* rp = P4 + (size_t)row * (VOCAB / 16);
  int cnt = 0;
  for (int j = threadIdx.x; j < VOCAB / 16; j += 256) {
    uint4 x = rp[j];
    cnt += __popc(x.x) + __popc(x.y) + __popc(x.z) + __popc(x.w);
  }
  #pragma unroll
  for (int off = 32; off > 0; off >>= 1) cnt += __shfl_down(cnt, off);
  __shared__ int ws[4];
  if ((threadIdx.x & 63) == 0) ws[threadIdx.x >> 6] = cnt;
  __syncthreads();
  if (threadIdx.x == 0)
    sizes[row] = (float)(ws[0] + ws[1] + ws[2] + ws[3]);
}

// ---------------- kernel 4: split-K i8 GEMM -> u16 partial tiles -------------
// grid (528, 2): x = triangle tile, y = K-slab. 128x128 tile, BK=64,
// 4 waves 2x2, each wave 4x4 of mfma_i32_16x16x64_i8.
// LDS XOR swizzle: 16B chunk kc of row r stored at slot (kc + (r>>1)) & 3.
__global__ __launch_bounds__(256) void gemm_kernel(
    const unsigned char* __restrict__ P,
    unsigned short* __restrict__ scratch) {  // partials live in the out buffer
  const int tile = blockIdx.x, slab = blockIdx.y;
  int b = tile, by = 0, rem = NTILE;
  while (b >= rem) { b -= rem; ++by; --rem; }
  const int bx = by + b;
  const int iBase = by * BM;
  const int jBase = bx * BN;

  __shared__ __align__(16) unsigned char As[BM * BK];  // 8 KB
  __shared__ __align__(16) unsigned char Bs[BN * BK];  // 8 KB

  const int tid  = threadIdx.x;
  const int wave = tid >> 6, lane = tid & 63;
  const int wm = wave >> 1, wn = wave & 1;
  const int col16 = lane & 15, quad = lane >> 4;

  intx4 acc[4][4];
  #pragma unroll
  for (int a = 0; a < 4; ++a)
    #pragma unroll
    for (int c = 0; c < 4; ++c) acc[a][c] = (intx4){0, 0, 0, 0};

  // staging: lane l stages row srow=l>>2 of its chunk, LDS slot sc=l&3.
  // slot sc holds global chunk kc = (sc - (row>>1)) & 3  (row>>1 == l>>3 here)
  const int srow = lane >> 2;
  const int scol = ((((lane & 3) - ((lane >> 3) & 3)) & 3) * 16);
  // fragment read slot offset: (quad + (row>>1)) & 3 with row>>1 == col16>>1
  const int rdoff = (((quad + (col16 >> 1)) & 3) * 16);

  const int k0base = slab * KSPLIT;
  for (int kk = 0; kk < KSPLIT; kk += BK) {
    const int k0 = k0base + kk;
    __syncthreads();
    #pragma unroll
    for (int t = 0; t < 2; ++t) {
      const int c = wave + t * 4;          // chunk 0..7 (16 rows each)
      const int r = c * 16 + srow;
      async_copy16(P + (size_t)(iBase + r) * VOCAB + k0 + scol, &As[c * 1024]);
      async_copy16(P + (size_t)(jBase + r) * VOCAB + k0 + scol, &Bs[c * 1024]);
    }
    __syncthreads();

    intx4 a[4], bfr[4];
    #pragma unroll
    for (int tm = 0; tm < 4; ++tm)
      a[tm] = *(const intx4*)&As[(wm * 64 + tm * 16 + col16) * BK + rdoff];
    #pragma unroll
    for (int tn = 0; tn < 4; ++tn)
      bfr[tn] = *(const intx4*)&Bs[(wn * 64 + tn * 16 + col16) * BK + rdoff];
    #pragma unroll
    for (int tm = 0; tm < 4; ++tm)
      #pragma unroll
      for (int tn = 0; tn < 4; ++tn)
        acc[tm][tn] = __builtin_amdgcn_mfma_i32_16x16x64_i8(
            a[tm], bfr[tn], acc[tm][tn], 0, 0, 0);
  }

  // write u16 partial tile (each value <= 256, fits u16)
  unsigned short* pp = scratch + ((size_t)slab * NTRI + tile) * (BM * BN);
  #pragma unroll
  for (int tm = 0; tm < 4; ++tm)
    #pragma unroll
    for (int tn = 0; tn < 4; ++tn) {
      const int colL = wn * 64 + tn * 16 + col16;
      #pragma unroll
      for (int r = 0; r < 4; ++r) {
        const int rowL = wm * 64 + tm * 16 + quad * 4 + r;
        pp[rowL * BN + colL] = (unsigned short)acc[tm][tn][r];
      }
    }
}

// ---------------- kernel 5: combine the two K-slab partials ------------------
// packed u16 pair add via u32 (each half <= 256, no carry)
__global__ void combine_kernel(const uint4* __restrict__ scratch,
                               uint4* __restrict__ summed) {
  const int tile = blockIdx.x;
  const uint4* s0 = scratch + (size_t)tile * (BM * BN / 8);
  const uint4* s1 = scratch + ((size_t)NTRI + tile) * (BM * BN / 8);
  uint4* d = summed + (size_t)tile * (BM * BN / 8);
  for (int k = 0; k < 8; ++k) {
    const int idx = threadIdx.x + k * 256;
    uint4 a = s0[idx], b = s1[idx];
    a.x += b.x; a.y += b.y; a.z += b.z; a.w += b.w;
    d[idx] = a;
  }
}

// ---------------- kernel 6: Jaccard epilogue (all 1024 tiles, fused mirror) --
__global__ void epilogue_kernel(const unsigned short* __restrict__ summed,
                                const float* __restrict__ sizes,
                                float* __restrict__ out) {
  const int bx = blockIdx.x, by = blockIdx.y;
  const int tid = threadIdx.x;
  const int r  = tid >> 1;          // local output row 0..127
  const int ch = tid & 1;           // column half
  const int R = by * BM + r;
  const float si = sizes[R];
  float* orow = out + (size_t)R * B_ROWS + bx * BN + ch * 64;

  if (bx >= by) {
    // straight read from summed[tri(by,bx)]
    const unsigned short* u = summed + (size_t)tri_index(by, bx) * (BM * BN);
    const uint4* up = (const uint4*)(u + r * BN + ch * 64);
    #pragma unroll
    for (int k = 0; k < 8; ++k) {   // 8 u16 per uint4
      uint4 w = up[k];
      unsigned int ww[4] = {w.x, w.y, w.z, w.w};
      #pragma unroll
      for (int q = 0; q < 4; ++q) {
        const int cbase = bx * BN + ch * 64 + k * 8 + q * 2;
        const float i0 = (float)(ww[q] & 0xFFFFu);
        const float i1 = (float)(ww[q] >> 16);
        const float u0 = si + sizes[cbase]     - i0;
        const float u1 = si + sizes[cbase + 1] - i1;
        orow[k * 8 + q * 2]     = (u0 != 0.f) ? (-i0 / u0) : 0.f;
        orow[k * 8 + q * 2 + 1] = (u1 != 0.f) ? (-i1 / u1) : 0.f;
      }
    }
  } else {
    // transposed read from summed[tri(bx,by)]: inter(R,C) = u[cL*128 + r]
    const unsigned short* u = summed + (size_t)tri_index(bx, by) * (BM * BN);
    #pragma unroll 8
    for (int i = 0; i < 64; ++i) {
      const int cL = ch * 64 + i;
      const float iv = (float)u[cL * BN + r];
      const float uv = si + sizes[bx * BN + cL] - iv;
      orow[i] = (uv != 0.f) ? (-iv / uv) : 0.f;
    }
  }
}

// ---------------- launcher ---------------------------------------------------
extern "C" void kernel_launch(void* const* d_in, const int* in_sizes, int n_in,
                              void* d_out, int out_size, void* d_ws, size_t ws_size,
                              hipStream_t stream) {
  const int* features = (const int*)d_in[0];
  float* out = (float*)d_out;
  // ws layout: [P 32MB][sizes 16KB][summed u16 17.3MB]  (~48.5 MiB total)
  unsigned char* P = (unsigned char*)d_ws;
  float* sizes = (float*)((char*)d_ws + (size_t)B_ROWS * VOCAB);
  unsigned short* summed =
      (unsigned short*)((char*)d_ws + (size_t)B_ROWS * VOCAB + 16384);
  // split-K partials live in the out buffer (34.6 MB <= 64 MB), consumed by
  // combine_kernel before epilogue_kernel overwrites out.
  unsigned short* scratch = (unsigned short*)d_out;

  zero_kernel<<<2048, 256, 0, stream>>>((uint4*)P, B_ROWS * VOCAB / 16);
  scatter_kernel<<<(B_ROWS * L_FEAT) / 256, 256, 0, stream>>>(features, P);
  sizes_kernel<<<B_ROWS, 256, 0, stream>>>((const uint4*)P, sizes);
  gemm_kernel<<<dim3(NTRI, 2), 256, 0, stream>>>(P, scratch);
  combine_kernel<<<NTRI, 256, 0, stream>>>((const uint4*)scratch, (uint4*)summed);
  epilogue_kernel<<<dim3(NTILE, NTILE), 256, 0, stream>>>(summed, sizes, out);
}

// Round 4
// 211.597 us; speedup vs baseline: 1.4311x; 1.4311x over previous
//
#include <hip/hip_runtime.h>
#include <hip/hip_bf16.h>
#include <stdint.h>

#define B_ROWS 4096
#define L_FEAT 256
#define VOCAB  8192

#define BM 128
#define BN 128
#define BK 64        // int8 MFMA K per iteration
#define NTILE 32     // 4096/128
#define NTRI  528    // NTILE*(NTILE+1)/2
#define KSPLIT 4096  // K per slab

typedef __attribute__((ext_vector_type(4))) int intx4;

__device__ __forceinline__ void async_copy16(const void* gsrc, void* ldst) {
  __builtin_amdgcn_global_load_lds(
      (const __attribute__((address_space(1))) void*)gsrc,
      (__attribute__((address_space(3))) void*)ldst, 16, 0, 0);
}

__device__ __forceinline__ int tri_index(int a, int b) {  // a<=b
  return a * NTILE - (a * (a - 1)) / 2 + (b - a);
}

// ---------------- kernel 1: zero the presence matrix (32 MB int8) ------------
__global__ void zero_kernel(uint4* __restrict__ p, int n16) {
  int i = blockIdx.x * blockDim.x + threadIdx.x;
  const int stride = gridDim.x * blockDim.x;
  const uint4 z = make_uint4(0u, 0u, 0u, 0u);
  for (; i < n16; i += stride) p[i] = z;
}

// ---------------- kernel 2: scatter ones (int8) ------------------------------
__global__ void scatter_kernel(const int* __restrict__ f,
                               unsigned char* __restrict__ P) {
  const int id  = blockIdx.x * 256 + threadIdx.x;
  const int row = id >> 8;
  const int v   = f[id];
  P[(size_t)row * VOCAB + v] = 1;
}

// ---------------- kernel 3: split-K i8 GEMM -> u16 partial tiles -------------
// grid (528, 2): x = triangle tile, y = K-slab. 128x128 tile, BK=64,
// 4 waves 2x2, each wave 4x4 of mfma_i32_16x16x64_i8.
// LDS XOR swizzle: 16B chunk kc of row r stored at slot (kc + (r>>1)) & 3.
__global__ __launch_bounds__(256) void gemm_kernel(
    const unsigned char* __restrict__ P,
    unsigned short* __restrict__ scratch) {  // partials live in the out buffer
  const int tile = blockIdx.x, slab = blockIdx.y;
  int b = tile, by = 0, rem = NTILE;
  while (b >= rem) { b -= rem; ++by; --rem; }
  const int bx = by + b;
  const int iBase = by * BM;
  const int jBase = bx * BN;

  __shared__ __align__(16) unsigned char As[BM * BK];  // 8 KB
  __shared__ __align__(16) unsigned char Bs[BN * BK];  // 8 KB

  const int tid  = threadIdx.x;
  const int wave = tid >> 6, lane = tid & 63;
  const int wm = wave >> 1, wn = wave & 1;
  const int col16 = lane & 15, quad = lane >> 4;

  intx4 acc[4][4];
  #pragma unroll
  for (int a = 0; a < 4; ++a)
    #pragma unroll
    for (int c = 0; c < 4; ++c) acc[a][c] = (intx4){0, 0, 0, 0};

  const int srow = lane >> 2;
  const int scol = ((((lane & 3) - ((lane >> 3) & 3)) & 3) * 16);
  const int rdoff = (((quad + (col16 >> 1)) & 3) * 16);

  const int k0base = slab * KSPLIT;
  for (int kk = 0; kk < KSPLIT; kk += BK) {
    const int k0 = k0base + kk;
    __syncthreads();
    #pragma unroll
    for (int t = 0; t < 2; ++t) {
      const int c = wave + t * 4;          // chunk 0..7 (16 rows each)
      const int r = c * 16 + srow;
      async_copy16(P + (size_t)(iBase + r) * VOCAB + k0 + scol, &As[c * 1024]);
      async_copy16(P + (size_t)(jBase + r) * VOCAB + k0 + scol, &Bs[c * 1024]);
    }
    __syncthreads();

    intx4 a[4], bfr[4];
    #pragma unroll
    for (int tm = 0; tm < 4; ++tm)
      a[tm] = *(const intx4*)&As[(wm * 64 + tm * 16 + col16) * BK + rdoff];
    #pragma unroll
    for (int tn = 0; tn < 4; ++tn)
      bfr[tn] = *(const intx4*)&Bs[(wn * 64 + tn * 16 + col16) * BK + rdoff];
    #pragma unroll
    for (int tm = 0; tm < 4; ++tm)
      #pragma unroll
      for (int tn = 0; tn < 4; ++tn)
        acc[tm][tn] = __builtin_amdgcn_mfma_i32_16x16x64_i8(
            a[tm], bfr[tn], acc[tm][tn], 0, 0, 0);
  }

  // write u16 partial tile (each value <= 256, fits u16)
  unsigned short* pp = scratch + ((size_t)slab * NTRI + tile) * (BM * BN);
  #pragma unroll
  for (int tm = 0; tm < 4; ++tm)
    #pragma unroll
    for (int tn = 0; tn < 4; ++tn) {
      const int colL = wn * 64 + tn * 16 + col16;
      #pragma unroll
      for (int r = 0; r < 4; ++r) {
        const int rowL = wm * 64 + tm * 16 + quad * 4 + r;
        pp[rowL * BN + colL] = (unsigned short)acc[tm][tn][r];
      }
    }
}

// ---------------- kernel 4: combine the two K-slab partials ------------------
// packed u16 pair add via u32 (each half <= 256, no carry)
__global__ void combine_kernel(const uint4* __restrict__ scratch,
                               uint4* __restrict__ summed) {
  const int tile = blockIdx.x;
  const uint4* s0 = scratch + (size_t)tile * (BM * BN / 8);
  const uint4* s1 = scratch + ((size_t)NTRI + tile) * (BM * BN / 8);
  uint4* d = summed + (size_t)tile * (BM * BN / 8);
  for (int k = 0; k < 8; ++k) {
    const int idx = threadIdx.x + k * 256;
    uint4 a = s0[idx], b = s1[idx];
    a.x += b.x; a.y += b.y; a.z += b.z; a.w += b.w;
    d[idx] = a;
  }
}

// ---------------- kernel 5: Jaccard epilogue, fused mirror, coalesced --------
// One block per triangle tile (a<=b). Row/col set sizes come from the
// diagonals of the diagonal tiles (inter(i,i) == |A_i|).
__global__ __launch_bounds__(256) void epilogue_kernel(
    const unsigned short* __restrict__ summed,
    float* __restrict__ out) {
  int t = blockIdx.x, a = 0, rem = NTILE;
  while (t >= rem) { t -= rem; ++a; --rem; }
  const int b = a + t;

  __shared__ float rowsz[128], colsz[128];
  __shared__ float ldsT[64 * 65];  // 16.6 KB transpose staging

  const int tid = threadIdx.x;
  {
    const unsigned short* dA = summed + (size_t)tri_index(a, a) * (BM * BN);
    const unsigned short* dB = summed + (size_t)tri_index(b, b) * (BM * BN);
    if (tid < 128) rowsz[tid] = (float)dA[tid * 129];
    else           colsz[tid - 128] = (float)dB[(tid - 128) * 129];
  }
  __syncthreads();

  const unsigned short* u = summed + (size_t)tri_index(a, b) * (BM * BN);

  // phase 1: upper tile (a,b) — ushort4 reads, float4 writes, coalesced
  {
    const int c4 = (tid & 31) * 4;
    const int rq = tid >> 5;  // 0..7
    #pragma unroll
    for (int rr = 0; rr < 16; ++rr) {
      const int r = rr * 8 + rq;
      const ushort4 v = *(const ushort4*)&u[r * BN + c4];
      const float si = rowsz[r];
      float4 o;
      float iv;
      iv = (float)v.x; o.x = -iv / (si + colsz[c4]     - iv);
      iv = (float)v.y; o.y = -iv / (si + colsz[c4 + 1] - iv);
      iv = (float)v.z; o.z = -iv / (si + colsz[c4 + 2] - iv);
      iv = (float)v.w; o.w = -iv / (si + colsz[c4 + 3] - iv);
      *(float4*)&out[(size_t)(a * BM + r) * B_ROWS + b * BN + c4] = o;
    }
  }

  // phase 2: mirror tile (b,a) via LDS transpose per 64x64 quadrant.
  // Stores transposed (scalar, stride 65 -> 2 lanes/bank, free), reads
  // straight (scalar, same pattern, free), global writes float4 coalesced.
  if (b > a) {
    const int c4q = (tid & 15) * 4;  // src cols / dest rows within quadrant
    const int rqq = tid >> 4;        // 0..15
    #pragma unroll
    for (int q = 0; q < 4; ++q) {
      const int qa = q >> 1, qb = q & 1;
      __syncthreads();  // guard LDS reuse across quadrants
      #pragma unroll
      for (int rr = 0; rr < 4; ++rr) {
        const int r = rr * 16 + rqq;  // src row-local 0..63
        const ushort4 v =
            *(const ushort4*)&u[(qa * 64 + r) * BN + qb * 64 + c4q];
        const float si = rowsz[qa * 64 + r];
        float iv;
        iv = (float)v.x;
        ldsT[(c4q + 0) * 65 + r] = -iv / (si + colsz[qb * 64 + c4q]     - iv);
        iv = (float)v.y;
        ldsT[(c4q + 1) * 65 + r] = -iv / (si + colsz[qb * 64 + c4q + 1] - iv);
        iv = (float)v.z;
        ldsT[(c4q + 2) * 65 + r] = -iv / (si + colsz[qb * 64 + c4q + 2] - iv);
        iv = (float)v.w;
        ldsT[(c4q + 3) * 65 + r] = -iv / (si + colsz[qb * 64 + c4q + 3] - iv);
      }
      __syncthreads();
      #pragma unroll
      for (int rr = 0; rr < 4; ++rr) {
        const int e = rr * 16 + rqq;  // dest row-local 0..63 (= src col)
        float4 o;
        o.x = ldsT[e * 65 + c4q];
        o.y = ldsT[e * 65 + c4q + 1];
        o.z = ldsT[e * 65 + c4q + 2];
        o.w = ldsT[e * 65 + c4q + 3];
        *(float4*)&out[(size_t)(b * BM + qb * 64 + e) * B_ROWS +
                       a * BN + qa * 64 + c4q] = o;
      }
    }
  }
}

// ---------------- launcher ---------------------------------------------------
extern "C" void kernel_launch(void* const* d_in, const int* in_sizes, int n_in,
                              void* d_out, int out_size, void* d_ws, size_t ws_size,
                              hipStream_t stream) {
  const int* features = (const int*)d_in[0];
  float* out = (float*)d_out;
  // ws layout: [P 32MB][summed u16 17.3MB]
  unsigned char* P = (unsigned char*)d_ws;
  unsigned short* summed = (unsigned short*)((char*)d_ws + (size_t)B_ROWS * VOCAB);
  // split-K partials live in the out buffer (34.6 MB <= 64 MB), fully consumed
  // by combine_kernel before epilogue_kernel overwrites out.
  unsigned short* scratch = (unsigned short*)d_out;

  zero_kernel<<<2048, 256, 0, stream>>>((uint4*)P, B_ROWS * VOCAB / 16);
  scatter_kernel<<<(B_ROWS * L_FEAT) / 256, 256, 0, stream>>>(features, P);
  gemm_kernel<<<dim3(NTRI, 2), 256, 0, stream>>>(P, scratch);
  combine_kernel<<<NTRI, 256, 0, stream>>>((const uint4*)scratch, (uint4*)summed);
  epilogue_kernel<<<NTRI, 256, 0, stream>>>(summed, out);
}